// Round 1
// baseline (463.558 us; speedup 1.0000x reference)
//
#include <hip/hip_runtime.h>
#include <hip/hip_bf16.h>

// ---------------------------------------------------------------------------
// Nemotron-H MoE: T=4096 H=1024 E=32 (top-8, grouped 8x4, topk_group=4)
// I=512, shared SI=2048, relu^2 MLPs, routed*2.5 + shared.
// Round 0: correctness-first fp16-MFMA grouped-GEMM pipeline.
// ---------------------------------------------------------------------------

typedef _Float16 h8 __attribute__((ext_vector_type(8)));
typedef _Float16 h4 __attribute__((ext_vector_type(4)));
typedef float f4 __attribute__((ext_vector_type(4)));

#define T_TOK 4096
#define HDIM  1024
#define NEXP  32
#define IDIM  512
#define SIDIM 2048
#define TOPK  8

// ---------------------------------------------------------------- cvt x->fp16
__global__ void cvt_x_kernel(const float* __restrict__ x, _Float16* __restrict__ xh) {
    int i = blockIdx.x * 256 + threadIdx.x;            // exactly T*H/4 threads
    float4 v = reinterpret_cast<const float4*>(x)[i];
    h4 o; o[0] = (_Float16)v.x; o[1] = (_Float16)v.y; o[2] = (_Float16)v.z; o[3] = (_Float16)v.w;
    reinterpret_cast<h4*>(xh)[i] = o;
}

// ---------------------------------------------------------------- router
// one wave per token; fp64 logits to match the (fp64) numpy reference's
// expert selection; serial grouped-topk on lane 0 (32 elements, trivial).
__global__ __launch_bounds__(256) void router_kernel(
    const float* __restrict__ x, const float* __restrict__ gw,
    const float* __restrict__ bias, int* __restrict__ topk_ids,
    float* __restrict__ topk_w) {
    const int wid  = threadIdx.x >> 6;
    const int lane = threadIdx.x & 63;
    const int t    = blockIdx.x * 4 + wid;
    const int e    = lane & 31;
    const int hh   = lane >> 5;   // which half of H this lane accumulates

    const float4* xr = reinterpret_cast<const float4*>(x  + (size_t)t * HDIM + hh * 512);
    const float4* gr = reinterpret_cast<const float4*>(gw + (size_t)e * HDIM + hh * 512);
    double a0 = 0.0, a1 = 0.0;
    for (int j = 0; j < 128; ++j) {
        float4 xv = xr[j], gv = gr[j];
        a0 += (double)xv.x * (double)gv.x + (double)xv.z * (double)gv.z;
        a1 += (double)xv.y * (double)gv.y + (double)xv.w * (double)gv.w;
    }
    double acc = a0 + a1;
    acc += __shfl_down(acc, 32);   // lanes 0..31 now hold full logits

    __shared__ double s_s[4][32];
    __shared__ double s_sfc[4][32];
    if (lane < 32) {
        double sg = 1.0 / (1.0 + exp(-acc));
        s_s[wid][lane]   = sg;
        s_sfc[wid][lane] = sg + (double)bias[e];
    }
    __syncthreads();

    if (lane == 0) {
        // group scores: sum of top-2 within each group of 4
        double gsc[8];
        for (int g = 0; g < 8; ++g) {
            double m1 = -1e300, m2 = -1e300;
            for (int j = 0; j < 4; ++j) {
                double v = s_sfc[wid][g * 4 + j];
                if (v > m1) { m2 = m1; m1 = v; } else if (v > m2) { m2 = v; }
            }
            gsc[g] = m1 + m2;
        }
        // top-4 groups (strict > keeps lowest index on ties, like lax.top_k)
        bool gsel[8] = {false, false, false, false, false, false, false, false};
        for (int r = 0; r < 4; ++r) {
            int best = 0; double bv = -1e300;
            for (int g = 0; g < 8; ++g)
                if (!gsel[g] && gsc[g] > bv) { bv = gsc[g]; best = g; }
            gsel[best] = true;
        }
        // top-8 experts among selected groups
        bool esel[32];
        for (int i2 = 0; i2 < 32; ++i2) esel[i2] = false;
        int ids[8]; double wsum = 0.0;
        for (int r = 0; r < 8; ++r) {
            int best = 0; double bv = -1e300;
            for (int e2 = 0; e2 < 32; ++e2)
                if (gsel[e2 >> 2] && !esel[e2] && s_sfc[wid][e2] > bv) { bv = s_sfc[wid][e2]; best = e2; }
            esel[best] = true;
            ids[r] = best;
            wsum += s_s[wid][best];
        }
        for (int r = 0; r < 8; ++r) {
            topk_ids[t * TOPK + r] = ids[r];
            // fold renormalization AND the final ROUTED_SCALE=2.5 into the weight
            topk_w[t * TOPK + r] = (float)(s_s[wid][ids[r]] / wsum * 2.5);
        }
    }
}

// ------------------------------------------------------- per-expert token lists
// deterministic (ordered by token index) ballot-compaction; one wave per expert.
__global__ void build_lists_kernel(const int* __restrict__ ids, const float* __restrict__ w,
                                   int* __restrict__ tok_list, float* __restrict__ wt_list,
                                   int* __restrict__ counts) {
    const int e = blockIdx.x;
    const int lane = threadIdx.x;  // block of 64
    int base = 0;
    for (int t0 = 0; t0 < T_TOK; t0 += 64) {
        int t = t0 + lane;
        int found = -1;
#pragma unroll
        for (int k = 0; k < TOPK; ++k)
            if (ids[t * TOPK + k] == e) found = k;
        unsigned long long mask = __ballot(found >= 0);
        if (found >= 0) {
            int pos = base + __popcll(mask & ((1ull << lane) - 1ull));
            tok_list[e * T_TOK + pos] = t;
            wt_list[e * T_TOK + pos]  = w[t * TOPK + found];
        }
        base += __popcll(mask);
    }
    if (lane == 0) counts[e] = base;
}

__global__ void scan_offsets_kernel(const int* __restrict__ counts, int* __restrict__ offsets) {
    if (threadIdx.x == 0) {
        int run = 0;
        for (int e = 0; e < NEXP; ++e) { offsets[e] = run; run += counts[e]; }
        offsets[NEXP] = run;
    }
}

// ---------------------------------------------------------------------------
// GEMM tile constants: 64x64 tile, BK=32, 256 threads (4 waves, 32x32/wave,
// 2x2 fragments of mfma_f32_16x16x32_f16). LDS padded to stride 40 halfs.
// A-fragment: lane holds 8 contiguous k at k=8*(lane>>4), row=lane&15.
// C/D: col=lane&15, row=4*(lane>>4)+reg (HW-verified mapping).
// ---------------------------------------------------------------------------

// ------------------------------------------------ routed up: h = relu(xW)^2 * w
__global__ __launch_bounds__(256) void up_routed_kernel(
    const _Float16* __restrict__ xh, const float* __restrict__ wup,
    const int* __restrict__ tok_list, const float* __restrict__ wt_list,
    const int* __restrict__ counts, const int* __restrict__ offsets,
    _Float16* __restrict__ hbuf) {
    const int e   = blockIdx.z;
    const int cnt = counts[e];
    const int m0  = blockIdx.y * 64;
    if (m0 >= cnt) return;
    const int n0   = blockIdx.x * 64;
    const int eoff = offsets[e];

    __shared__ __attribute__((aligned(16))) _Float16 As[64][40];
    __shared__ __attribute__((aligned(16))) _Float16 Bs[64][40];
    __shared__ int   tokS[64];
    __shared__ float wS[64];

    const int tid = threadIdx.x;
    if (tid < 64) {
        int row = m0 + tid;
        bool ok = row < cnt;
        tokS[tid] = ok ? tok_list[e * T_TOK + row] : 0;
        wS[tid]   = ok ? wt_list[e * T_TOK + row] : 0.0f;
    }
    __syncthreads();

    const int lane = tid & 63, wid = tid >> 6;
    const int moff = (wid & 1) * 32, noff = (wid >> 1) * 32;
    const int ra = lane & 15, kb = (lane >> 4) << 3;
    const int sr = tid >> 2, sg = (tid & 3) << 3;
    const int tok = tokS[sr];
    const float* bsrc = wup + ((size_t)e * IDIM + n0 + sr) * HDIM + sg;
    const _Float16* asrc = xh + (size_t)tok * HDIM + sg;

    f4 acc[2][2] = {};
    // prologue prefetch
    float4 va  = *reinterpret_cast<const float4*>(asrc);
    float4 vb0 = *reinterpret_cast<const float4*>(bsrc);
    float4 vb1 = *reinterpret_cast<const float4*>(bsrc + 4);

    for (int kk = 0; kk < HDIM; kk += 32) {
        *reinterpret_cast<float4*>(&As[sr][sg]) = va;   // 8 halfs raw
        h8 hb;
        hb[0]=(_Float16)vb0.x; hb[1]=(_Float16)vb0.y; hb[2]=(_Float16)vb0.z; hb[3]=(_Float16)vb0.w;
        hb[4]=(_Float16)vb1.x; hb[5]=(_Float16)vb1.y; hb[6]=(_Float16)vb1.z; hb[7]=(_Float16)vb1.w;
        *reinterpret_cast<h8*>(&Bs[sr][sg]) = hb;
        __syncthreads();
        if (kk + 32 < HDIM) {   // prefetch next K-tile under the MFMAs
            va  = *reinterpret_cast<const float4*>(asrc + kk + 32);
            vb0 = *reinterpret_cast<const float4*>(bsrc + kk + 32);
            vb1 = *reinterpret_cast<const float4*>(bsrc + kk + 36);
        }
        h8 a0 = *reinterpret_cast<h8*>(&As[moff + ra][kb]);
        h8 a1 = *reinterpret_cast<h8*>(&As[moff + 16 + ra][kb]);
        h8 b0 = *reinterpret_cast<h8*>(&Bs[noff + ra][kb]);
        h8 b1 = *reinterpret_cast<h8*>(&Bs[noff + 16 + ra][kb]);
        acc[0][0] = __builtin_amdgcn_mfma_f32_16x16x32_f16(a0, b0, acc[0][0], 0, 0, 0);
        acc[0][1] = __builtin_amdgcn_mfma_f32_16x16x32_f16(a0, b1, acc[0][1], 0, 0, 0);
        acc[1][0] = __builtin_amdgcn_mfma_f32_16x16x32_f16(a1, b0, acc[1][0], 0, 0, 0);
        acc[1][1] = __builtin_amdgcn_mfma_f32_16x16x32_f16(a1, b1, acc[1][1], 0, 0, 0);
        __syncthreads();
    }
#pragma unroll
    for (int fm = 0; fm < 2; ++fm)
#pragma unroll
    for (int fn = 0; fn < 2; ++fn)
#pragma unroll
    for (int r = 0; r < 4; ++r) {
        int rl = moff + fm * 16 + ((lane >> 4) << 2) + r;
        int cl = noff + fn * 16 + (lane & 15);
        int grow = m0 + rl;
        if (grow < cnt) {
            float v = acc[fm][fn][r];
            v = fmaxf(v, 0.0f);
            v = v * v * wS[rl];
            hbuf[(size_t)(eoff + grow) * IDIM + n0 + cl] = (_Float16)v;
        }
    }
}

// ------------------------------------------------ routed down: out += h @ Wd^T
__global__ __launch_bounds__(256) void down_routed_kernel(
    const _Float16* __restrict__ hbuf, const float* __restrict__ wdown,
    const int* __restrict__ tok_list, const int* __restrict__ counts,
    const int* __restrict__ offsets, float* __restrict__ out) {
    const int e   = blockIdx.z;
    const int cnt = counts[e];
    const int m0  = blockIdx.y * 64;
    if (m0 >= cnt) return;
    const int n0   = blockIdx.x * 64;
    const int eoff = offsets[e];

    __shared__ __attribute__((aligned(16))) _Float16 As[64][40];
    __shared__ __attribute__((aligned(16))) _Float16 Bs[64][40];
    __shared__ int tokS[64];

    const int tid = threadIdx.x;
    if (tid < 64) {
        int row = m0 + tid;
        tokS[tid] = (row < cnt) ? tok_list[e * T_TOK + row] : 0;
    }
    __syncthreads();

    const int lane = tid & 63, wid = tid >> 6;
    const int moff = (wid & 1) * 32, noff = (wid >> 1) * 32;
    const int ra = lane & 15, kb = (lane >> 4) << 3;
    const int sr = tid >> 2, sg = (tid & 3) << 3;
    const bool avalid = (m0 + sr) < cnt;
    const _Float16* asrc = hbuf + (size_t)(eoff + m0 + sr) * IDIM + sg;
    const float* bsrc = wdown + ((size_t)e * HDIM + n0 + sr) * IDIM + sg;

    f4 acc[2][2] = {};
    float4 zero4 = {0.f, 0.f, 0.f, 0.f};
    float4 va  = avalid ? *reinterpret_cast<const float4*>(asrc) : zero4;
    float4 vb0 = *reinterpret_cast<const float4*>(bsrc);
    float4 vb1 = *reinterpret_cast<const float4*>(bsrc + 4);

    for (int kk = 0; kk < IDIM; kk += 32) {
        *reinterpret_cast<float4*>(&As[sr][sg]) = va;
        h8 hb;
        hb[0]=(_Float16)vb0.x; hb[1]=(_Float16)vb0.y; hb[2]=(_Float16)vb0.z; hb[3]=(_Float16)vb0.w;
        hb[4]=(_Float16)vb1.x; hb[5]=(_Float16)vb1.y; hb[6]=(_Float16)vb1.z; hb[7]=(_Float16)vb1.w;
        *reinterpret_cast<h8*>(&Bs[sr][sg]) = hb;
        __syncthreads();
        if (kk + 32 < IDIM) {
            va  = avalid ? *reinterpret_cast<const float4*>(asrc + kk + 32) : zero4;
            vb0 = *reinterpret_cast<const float4*>(bsrc + kk + 32);
            vb1 = *reinterpret_cast<const float4*>(bsrc + kk + 36);
        }
        h8 a0 = *reinterpret_cast<h8*>(&As[moff + ra][kb]);
        h8 a1 = *reinterpret_cast<h8*>(&As[moff + 16 + ra][kb]);
        h8 b0 = *reinterpret_cast<h8*>(&Bs[noff + ra][kb]);
        h8 b1 = *reinterpret_cast<h8*>(&Bs[noff + 16 + ra][kb]);
        acc[0][0] = __builtin_amdgcn_mfma_f32_16x16x32_f16(a0, b0, acc[0][0], 0, 0, 0);
        acc[0][1] = __builtin_amdgcn_mfma_f32_16x16x32_f16(a0, b1, acc[0][1], 0, 0, 0);
        acc[1][0] = __builtin_amdgcn_mfma_f32_16x16x32_f16(a1, b0, acc[1][0], 0, 0, 0);
        acc[1][1] = __builtin_amdgcn_mfma_f32_16x16x32_f16(a1, b1, acc[1][1], 0, 0, 0);
        __syncthreads();
    }
#pragma unroll
    for (int fm = 0; fm < 2; ++fm)
#pragma unroll
    for (int fn = 0; fn < 2; ++fn)
#pragma unroll
    for (int r = 0; r < 4; ++r) {
        int rl = moff + fm * 16 + ((lane >> 4) << 2) + r;
        int cl = noff + fn * 16 + (lane & 15);
        int grow = m0 + rl;
        if (grow < cnt)
            atomicAdd(&out[(size_t)tokS[rl] * HDIM + n0 + cl], acc[fm][fn][r]);
    }
}

// ------------------------------------------------ shared up: sh = relu(x Su^T)^2
__global__ __launch_bounds__(256) void up_shared_kernel(
    const _Float16* __restrict__ xh, const float* __restrict__ sup,
    _Float16* __restrict__ sh) {
    const int m0 = blockIdx.y * 64;
    const int n0 = blockIdx.x * 64;

    __shared__ __attribute__((aligned(16))) _Float16 As[64][40];
    __shared__ __attribute__((aligned(16))) _Float16 Bs[64][40];

    const int tid = threadIdx.x;
    const int lane = tid & 63, wid = tid >> 6;
    const int moff = (wid & 1) * 32, noff = (wid >> 1) * 32;
    const int ra = lane & 15, kb = (lane >> 4) << 3;
    const int sr = tid >> 2, sg = (tid & 3) << 3;
    const _Float16* asrc = xh + (size_t)(m0 + sr) * HDIM + sg;
    const float* bsrc = sup + (size_t)(n0 + sr) * HDIM + sg;

    f4 acc[2][2] = {};
    float4 va  = *reinterpret_cast<const float4*>(asrc);
    float4 vb0 = *reinterpret_cast<const float4*>(bsrc);
    float4 vb1 = *reinterpret_cast<const float4*>(bsrc + 4);

    for (int kk = 0; kk < HDIM; kk += 32) {
        *reinterpret_cast<float4*>(&As[sr][sg]) = va;
        h8 hb;
        hb[0]=(_Float16)vb0.x; hb[1]=(_Float16)vb0.y; hb[2]=(_Float16)vb0.z; hb[3]=(_Float16)vb0.w;
        hb[4]=(_Float16)vb1.x; hb[5]=(_Float16)vb1.y; hb[6]=(_Float16)vb1.z; hb[7]=(_Float16)vb1.w;
        *reinterpret_cast<h8*>(&Bs[sr][sg]) = hb;
        __syncthreads();
        if (kk + 32 < HDIM) {
            va  = *reinterpret_cast<const float4*>(asrc + kk + 32);
            vb0 = *reinterpret_cast<const float4*>(bsrc + kk + 32);
            vb1 = *reinterpret_cast<const float4*>(bsrc + kk + 36);
        }
        h8 a0 = *reinterpret_cast<h8*>(&As[moff + ra][kb]);
        h8 a1 = *reinterpret_cast<h8*>(&As[moff + 16 + ra][kb]);
        h8 b0 = *reinterpret_cast<h8*>(&Bs[noff + ra][kb]);
        h8 b1 = *reinterpret_cast<h8*>(&Bs[noff + 16 + ra][kb]);
        acc[0][0] = __builtin_amdgcn_mfma_f32_16x16x32_f16(a0, b0, acc[0][0], 0, 0, 0);
        acc[0][1] = __builtin_amdgcn_mfma_f32_16x16x32_f16(a0, b1, acc[0][1], 0, 0, 0);
        acc[1][0] = __builtin_amdgcn_mfma_f32_16x16x32_f16(a1, b0, acc[1][0], 0, 0, 0);
        acc[1][1] = __builtin_amdgcn_mfma_f32_16x16x32_f16(a1, b1, acc[1][1], 0, 0, 0);
        __syncthreads();
    }
#pragma unroll
    for (int fm = 0; fm < 2; ++fm)
#pragma unroll
    for (int fn = 0; fn < 2; ++fn)
#pragma unroll
    for (int r = 0; r < 4; ++r) {
        int rl = moff + fm * 16 + ((lane >> 4) << 2) + r;
        int cl = noff + fn * 16 + (lane & 15);
        float v = acc[fm][fn][r];
        v = fmaxf(v, 0.0f);
        v = v * v;
        sh[(size_t)(m0 + rl) * SIDIM + n0 + cl] = (_Float16)v;
    }
}

// ------------------------------------------------ shared down: out = sh @ Sd^T
__global__ __launch_bounds__(256) void down_shared_kernel(
    const _Float16* __restrict__ sh, const float* __restrict__ sdown,
    float* __restrict__ out) {
    const int m0 = blockIdx.y * 64;
    const int n0 = blockIdx.x * 64;

    __shared__ __attribute__((aligned(16))) _Float16 As[64][40];
    __shared__ __attribute__((aligned(16))) _Float16 Bs[64][40];

    const int tid = threadIdx.x;
    const int lane = tid & 63, wid = tid >> 6;
    const int moff = (wid & 1) * 32, noff = (wid >> 1) * 32;
    const int ra = lane & 15, kb = (lane >> 4) << 3;
    const int sr = tid >> 2, sg = (tid & 3) << 3;
    const _Float16* asrc = sh + (size_t)(m0 + sr) * SIDIM + sg;
    const float* bsrc = sdown + (size_t)(n0 + sr) * SIDIM + sg;

    f4 acc[2][2] = {};
    float4 va  = *reinterpret_cast<const float4*>(asrc);
    float4 vb0 = *reinterpret_cast<const float4*>(bsrc);
    float4 vb1 = *reinterpret_cast<const float4*>(bsrc + 4);

    for (int kk = 0; kk < SIDIM; kk += 32) {
        *reinterpret_cast<float4*>(&As[sr][sg]) = va;
        h8 hb;
        hb[0]=(_Float16)vb0.x; hb[1]=(_Float16)vb0.y; hb[2]=(_Float16)vb0.z; hb[3]=(_Float16)vb0.w;
        hb[4]=(_Float16)vb1.x; hb[5]=(_Float16)vb1.y; hb[6]=(_Float16)vb1.z; hb[7]=(_Float16)vb1.w;
        *reinterpret_cast<h8*>(&Bs[sr][sg]) = hb;
        __syncthreads();
        if (kk + 32 < SIDIM) {
            va  = *reinterpret_cast<const float4*>(asrc + kk + 32);
            vb0 = *reinterpret_cast<const float4*>(bsrc + kk + 32);
            vb1 = *reinterpret_cast<const float4*>(bsrc + kk + 36);
        }
        h8 a0 = *reinterpret_cast<h8*>(&As[moff + ra][kb]);
        h8 a1 = *reinterpret_cast<h8*>(&As[moff + 16 + ra][kb]);
        h8 b0 = *reinterpret_cast<h8*>(&Bs[noff + ra][kb]);
        h8 b1 = *reinterpret_cast<h8*>(&Bs[noff + 16 + ra][kb]);
        acc[0][0] = __builtin_amdgcn_mfma_f32_16x16x32_f16(a0, b0, acc[0][0], 0, 0, 0);
        acc[0][1] = __builtin_amdgcn_mfma_f32_16x16x32_f16(a0, b1, acc[0][1], 0, 0, 0);
        acc[1][0] = __builtin_amdgcn_mfma_f32_16x16x32_f16(a1, b0, acc[1][0], 0, 0, 0);
        acc[1][1] = __builtin_amdgcn_mfma_f32_16x16x32_f16(a1, b1, acc[1][1], 0, 0, 0);
        __syncthreads();
    }
#pragma unroll
    for (int fm = 0; fm < 2; ++fm)
#pragma unroll
    for (int fn = 0; fn < 2; ++fn)
#pragma unroll
    for (int r = 0; r < 4; ++r) {
        int rl = moff + fm * 16 + ((lane >> 4) << 2) + r;
        int cl = noff + fn * 16 + (lane & 15);
        out[(size_t)(m0 + rl) * HDIM + n0 + cl] = acc[fm][fn][r];
    }
}

// ---------------------------------------------------------------------------
extern "C" void kernel_launch(void* const* d_in, const int* in_sizes, int n_in,
                              void* d_out, int out_size, void* d_ws, size_t ws_size,
                              hipStream_t stream) {
    const float* x     = (const float*)d_in[0];
    const float* gw    = (const float*)d_in[1];
    const float* bias  = (const float*)d_in[2];
    const float* wup   = (const float*)d_in[3];
    const float* wdown = (const float*)d_in[4];
    const float* sup   = (const float*)d_in[5];
    const float* sdown = (const float*)d_in[6];
    float* out = (float*)d_out;

    char* ws = (char*)d_ws;
    size_t off = 0;
    auto take = [&](size_t bytes) {
        char* p = ws + off;
        off = (off + bytes + 255) & ~(size_t)255;
        return p;
    };
    _Float16* xh   = (_Float16*)take((size_t)T_TOK * HDIM * 2);        // 8 MB
    _Float16* sh   = (_Float16*)take((size_t)T_TOK * SIDIM * 2);       // 16 MB
    _Float16* hbuf = (_Float16*)take((size_t)T_TOK * TOPK * IDIM * 2); // 32 MB
    int*   ids      = (int*)take((size_t)T_TOK * TOPK * 4);
    float* tw       = (float*)take((size_t)T_TOK * TOPK * 4);
    int*   tok_list = (int*)take((size_t)NEXP * T_TOK * 4);
    float* wt_list  = (float*)take((size_t)NEXP * T_TOK * 4);
    int*   counts   = (int*)take(NEXP * 4);
    int*   offsets  = (int*)take((NEXP + 1) * 4);

    cvt_x_kernel<<<T_TOK * HDIM / 4 / 256, 256, 0, stream>>>(x, xh);
    router_kernel<<<T_TOK / 4, 256, 0, stream>>>(x, gw, bias, ids, tw);
    build_lists_kernel<<<NEXP, 64, 0, stream>>>(ids, tw, tok_list, wt_list, counts);
    scan_offsets_kernel<<<1, 64, 0, stream>>>(counts, offsets);

    // routed up: [cnt_e,1024] x [512,1024]^T -> h (relu^2 * gate*2.5, fp16)
    up_routed_kernel<<<dim3(IDIM / 64, T_TOK / 64, NEXP), 256, 0, stream>>>(
        xh, wup, tok_list, wt_list, counts, offsets, hbuf);
    // shared up: [4096,1024] x [2048,1024]^T -> sh (relu^2, fp16)
    up_shared_kernel<<<dim3(SIDIM / 64, T_TOK / 64), 256, 0, stream>>>(xh, sup, sh);
    // shared down writes the output base...
    down_shared_kernel<<<dim3(HDIM / 64, T_TOK / 64), 256, 0, stream>>>(sh, sdown, out);
    // ...then routed down atomically accumulates on top (stream-ordered).
    down_routed_kernel<<<dim3(HDIM / 64, T_TOK / 64, NEXP), 256, 0, stream>>>(
        hbuf, wdown, tok_list, counts, offsets, out);
}

// Round 2
// 399.760 us; speedup vs baseline: 1.1596x; 1.1596x over previous
//
#include <hip/hip_runtime.h>
#include <hip/hip_bf16.h>

// ---------------------------------------------------------------------------
// Nemotron-H MoE: T=4096 H=1024 E=32 (top-8, grouped 8x4) I=512, SI=2048.
// Round 2: fp16 weight pre-convert + 128x128 BK=64 GEMMs with
// global_load_lds(16) + source-side XOR swizzle; atomic-free down combine.
// ---------------------------------------------------------------------------

typedef _Float16 h8 __attribute__((ext_vector_type(8)));
typedef _Float16 h4 __attribute__((ext_vector_type(4)));
typedef float f4 __attribute__((ext_vector_type(4)));

#define T_TOK 4096
#define HDIM  1024
#define NEXP  32
#define IDIM  512
#define SIDIM 2048
#define TOPK  8

// async global->LDS, 16B per lane; LDS dest = wave-uniform base + lane*16
__device__ __forceinline__ void gload16(const void* g, void* l) {
    __builtin_amdgcn_global_load_lds(
        (const __attribute__((address_space(1))) void*)g,
        (__attribute__((address_space(3))) void*)l, 16, 0, 0);
}

// ---------------------------------------------------------------- fp32->fp16
__global__ void cvt_kernel(const float* __restrict__ in, _Float16* __restrict__ o, int n4) {
    int i = blockIdx.x * 256 + threadIdx.x;
    if (i < n4) {
        float4 v = reinterpret_cast<const float4*>(in)[i];
        h4 h; h[0] = (_Float16)v.x; h[1] = (_Float16)v.y; h[2] = (_Float16)v.z; h[3] = (_Float16)v.w;
        reinterpret_cast<h4*>(o)[i] = h;
    }
}

// ---------------------------------------------------------------- router (fp64)
__global__ __launch_bounds__(256) void router_kernel(
    const float* __restrict__ x, const float* __restrict__ gw,
    const float* __restrict__ bias, int* __restrict__ topk_ids,
    float* __restrict__ topk_w) {
    const int wid  = threadIdx.x >> 6;
    const int lane = threadIdx.x & 63;
    const int t    = blockIdx.x * 4 + wid;
    const int e    = lane & 31;
    const int hh   = lane >> 5;

    const float4* xr = reinterpret_cast<const float4*>(x  + (size_t)t * HDIM + hh * 512);
    const float4* gr = reinterpret_cast<const float4*>(gw + (size_t)e * HDIM + hh * 512);
    double a0 = 0.0, a1 = 0.0;
    for (int j = 0; j < 128; ++j) {
        float4 xv = xr[j], gv = gr[j];
        a0 += (double)xv.x * (double)gv.x + (double)xv.z * (double)gv.z;
        a1 += (double)xv.y * (double)gv.y + (double)xv.w * (double)gv.w;
    }
    double acc = a0 + a1;
    acc += __shfl_down(acc, 32);

    __shared__ double s_s[4][32];
    __shared__ double s_sfc[4][32];
    if (lane < 32) {
        double sg = 1.0 / (1.0 + exp(-acc));
        s_s[wid][lane]   = sg;
        s_sfc[wid][lane] = sg + (double)bias[e];
    }
    __syncthreads();

    if (lane == 0) {
        double gsc[8];
        for (int g = 0; g < 8; ++g) {
            double m1 = -1e300, m2 = -1e300;
            for (int j = 0; j < 4; ++j) {
                double v = s_sfc[wid][g * 4 + j];
                if (v > m1) { m2 = m1; m1 = v; } else if (v > m2) { m2 = v; }
            }
            gsc[g] = m1 + m2;
        }
        bool gsel[8] = {};
        for (int r = 0; r < 4; ++r) {
            int best = 0; double bv = -1e300;
            for (int g = 0; g < 8; ++g)
                if (!gsel[g] && gsc[g] > bv) { bv = gsc[g]; best = g; }
            gsel[best] = true;
        }
        bool esel[32];
        for (int i2 = 0; i2 < 32; ++i2) esel[i2] = false;
        int ids[8]; double wsum = 0.0;
        for (int r = 0; r < 8; ++r) {
            int best = 0; double bv = -1e300;
            for (int e2 = 0; e2 < 32; ++e2)
                if (gsel[e2 >> 2] && !esel[e2] && s_sfc[wid][e2] > bv) { bv = s_sfc[wid][e2]; best = e2; }
            esel[best] = true;
            ids[r] = best;
            wsum += s_s[wid][best];
        }
        for (int r = 0; r < 8; ++r) {
            topk_ids[t * TOPK + r] = ids[r];
            topk_w[t * TOPK + r] = (float)(s_s[wid][ids[r]] / wsum * 2.5);
        }
    }
}

// ------------------------------------------------------- per-expert token lists
__global__ void build_lists_kernel(const int* __restrict__ ids, const float* __restrict__ w,
                                   int* __restrict__ tok_list, float* __restrict__ wt_list,
                                   int* __restrict__ dest_list, int* __restrict__ counts) {
    const int e = blockIdx.x;
    const int lane = threadIdx.x;  // block of 64
    int base = 0;
    for (int t0 = 0; t0 < T_TOK; t0 += 64) {
        int t = t0 + lane;
        int found = -1;
#pragma unroll
        for (int k = 0; k < TOPK; ++k)
            if (ids[t * TOPK + k] == e) found = k;
        unsigned long long mask = __ballot(found >= 0);
        if (found >= 0) {
            int pos = base + __popcll(mask & ((1ull << lane) - 1ull));
            tok_list[e * T_TOK + pos]  = t;
            wt_list[e * T_TOK + pos]   = w[t * TOPK + found];
            dest_list[e * T_TOK + pos] = t * TOPK + found;
        }
        base += __popcll(mask);
    }
    if (lane == 0) counts[e] = base;
}

__global__ void scan_offsets_kernel(const int* __restrict__ counts, int* __restrict__ offsets) {
    if (threadIdx.x == 0) {
        int run = 0;
        for (int e = 0; e < NEXP; ++e) { offsets[e] = run; run += counts[e]; }
        offsets[NEXP] = run;
    }
}

// ---------------------------------------------------------------------------
// Core 128x128 GEMM tile, BK=64, 256 threads (4 waves, 64x64 each, 4x4
// 16x16x32_f16 fragments). Linear LDS [128][64] halfs staged via
// global_load_lds(16B); XOR chunk swizzle applied on the global SOURCE
// address (rule: linear dest + inverse-swz source + swz read).
// aSrc/bSrc: per-thread pointers (incl. swizzle chunk), advanced by kk.
// ---------------------------------------------------------------------------
template<int K>
__device__ __forceinline__ void gemm128(const _Float16* const (&aSrc)[4],
                                        const _Float16* const (&bSrc)[4],
                                        f4 (&acc)[4][4]) {
    __shared__ __attribute__((aligned(16))) _Float16 As[128 * 64];
    __shared__ __attribute__((aligned(16))) _Float16 Bs[128 * 64];
    const int tid  = threadIdx.x;
    const int w    = tid >> 6, lane = tid & 63;
    const int wm   = (w & 1) * 64, wn = (w >> 1) * 64;
    const int ra   = lane & 15, kq = lane >> 4;

    for (int kk = 0; kk < K; kk += 64) {
#pragma unroll
        for (int i = 0; i < 4; ++i) {
            gload16(aSrc[i] + kk, As + (size_t)(i * 256 + w * 64) * 8);
            gload16(bSrc[i] + kk, Bs + (size_t)(i * 256 + w * 64) * 8);
        }
        __syncthreads();
#pragma unroll
        for (int s = 0; s < 2; ++s) {
            h8 af[4], bf[4];
#pragma unroll
            for (int m = 0; m < 4; ++m) {
                int row = wm + m * 16 + ra;
                af[m] = *reinterpret_cast<const h8*>(As + row * 64 + (((s * 4 + kq) ^ (row & 7)) << 3));
            }
#pragma unroll
            for (int n = 0; n < 4; ++n) {
                int row = wn + n * 16 + ra;
                bf[n] = *reinterpret_cast<const h8*>(Bs + row * 64 + (((s * 4 + kq) ^ (row & 7)) << 3));
            }
#pragma unroll
            for (int m = 0; m < 4; ++m)
#pragma unroll
                for (int n = 0; n < 4; ++n)
                    acc[m][n] = __builtin_amdgcn_mfma_f32_16x16x32_f16(af[m], bf[n], acc[m][n], 0, 0, 0);
        }
        __syncthreads();
    }
}

// ------------------------------------------------ routed up: h = relu(xW)^2 * g
__global__ __launch_bounds__(256) void up_routed_kernel(
    const _Float16* __restrict__ xh, const _Float16* __restrict__ whup,
    const int* __restrict__ tok_list, const float* __restrict__ wt_list,
    const int* __restrict__ counts, const int* __restrict__ offsets,
    _Float16* __restrict__ hbuf) {
    const int e   = blockIdx.z;
    const int cnt = counts[e];
    const int m0  = blockIdx.y * 128;
    if (m0 >= cnt) return;
    const int n0   = blockIdx.x * 128;
    const int eoff = offsets[e];

    __shared__ int   tokS[128];
    __shared__ float wS[128];
    const int tid = threadIdx.x;
    if (tid < 128) {
        int row = m0 + tid;
        int cr  = row < cnt ? row : cnt - 1;
        tokS[tid] = tok_list[e * T_TOK + cr];
        wS[tid]   = row < cnt ? wt_list[e * T_TOK + row] : 0.f;
    }
    __syncthreads();

    const int sc = ((tid & 7) ^ ((tid >> 3) & 7)) << 3;
    const int r0 = tid >> 3;
    const _Float16* aSrc[4]; const _Float16* bSrc[4];
#pragma unroll
    for (int i = 0; i < 4; ++i) {
        aSrc[i] = xh + (size_t)tokS[i * 32 + r0] * HDIM + sc;
        bSrc[i] = whup + ((size_t)e * IDIM + n0 + i * 32 + r0) * HDIM + sc;
    }
    f4 acc[4][4] = {};
    gemm128<HDIM>(aSrc, bSrc, acc);

    const int w = tid >> 6, lane = tid & 63;
    const int wm = (w & 1) * 64, wn = (w >> 1) * 64;
    const int cq = lane >> 4, cc = lane & 15;
#pragma unroll
    for (int m = 0; m < 4; ++m)
#pragma unroll
    for (int r = 0; r < 4; ++r) {
        int orow = wm + m * 16 + cq * 4 + r;
        if (m0 + orow < cnt) {
            float g = wS[orow];
            size_t rb = (size_t)(eoff + m0 + orow) * IDIM + n0;
#pragma unroll
            for (int n = 0; n < 4; ++n) {
                float v = fmaxf(acc[m][n][r], 0.f);
                hbuf[rb + wn + n * 16 + cc] = (_Float16)(v * v * g);
            }
        }
    }
}

// ------------------------------------------------ routed down
template<bool SLOT>
__global__ __launch_bounds__(256) void down_routed_kernel(
    const _Float16* __restrict__ hbuf, const _Float16* __restrict__ whdown,
    const int* __restrict__ dest_list, const int* __restrict__ counts,
    const int* __restrict__ offsets, _Float16* __restrict__ slotout,
    float* __restrict__ out) {
    const int e   = blockIdx.z;
    const int cnt = counts[e];
    const int m0  = blockIdx.y * 128;
    if (m0 >= cnt) return;
    const int n0   = blockIdx.x * 128;
    const int eoff = offsets[e];

    __shared__ int dS[128];
    const int tid = threadIdx.x;
    if (tid < 128) {
        int row = m0 + tid;
        dS[tid] = dest_list[e * T_TOK + (row < cnt ? row : cnt - 1)];
    }
    // (dS is consumed only after gemm128's internal barriers)

    const int sc = ((tid & 7) ^ ((tid >> 3) & 7)) << 3;
    const int r0 = tid >> 3;
    const _Float16* aSrc[4]; const _Float16* bSrc[4];
#pragma unroll
    for (int i = 0; i < 4; ++i) {
        int row = m0 + i * 32 + r0;
        int cr  = row < cnt ? row : cnt - 1;
        aSrc[i] = hbuf + (size_t)(eoff + cr) * IDIM + sc;
        bSrc[i] = whdown + ((size_t)e * HDIM + n0 + i * 32 + r0) * IDIM + sc;
    }
    f4 acc[4][4] = {};
    gemm128<IDIM>(aSrc, bSrc, acc);

    const int w = tid >> 6, lane = tid & 63;
    const int wm = (w & 1) * 64, wn = (w >> 1) * 64;
    const int cq = lane >> 4, cc = lane & 15;
#pragma unroll
    for (int m = 0; m < 4; ++m)
#pragma unroll
    for (int r = 0; r < 4; ++r) {
        int orow = wm + m * 16 + cq * 4 + r;
        if (m0 + orow < cnt) {
            int d = dS[orow];
            if (SLOT) {
                size_t rb = (size_t)d * HDIM + n0;
#pragma unroll
                for (int n = 0; n < 4; ++n)
                    slotout[rb + wn + n * 16 + cc] = (_Float16)acc[m][n][r];
            } else {
                size_t rb = (size_t)(d >> 3) * HDIM + n0;
#pragma unroll
                for (int n = 0; n < 4; ++n)
                    atomicAdd(&out[rb + wn + n * 16 + cc], acc[m][n][r]);
            }
        }
    }
}

// ------------------------------------------------ shared up
__global__ __launch_bounds__(256) void up_shared_kernel(
    const _Float16* __restrict__ xh, const _Float16* __restrict__ shup,
    _Float16* __restrict__ sh) {
    const int m0 = blockIdx.y * 128;
    const int n0 = blockIdx.x * 128;
    const int tid = threadIdx.x;
    const int sc = ((tid & 7) ^ ((tid >> 3) & 7)) << 3;
    const int r0 = tid >> 3;
    const _Float16* aSrc[4]; const _Float16* bSrc[4];
#pragma unroll
    for (int i = 0; i < 4; ++i) {
        aSrc[i] = xh + (size_t)(m0 + i * 32 + r0) * HDIM + sc;
        bSrc[i] = shup + (size_t)(n0 + i * 32 + r0) * HDIM + sc;
    }
    f4 acc[4][4] = {};
    gemm128<HDIM>(aSrc, bSrc, acc);

    const int w = tid >> 6, lane = tid & 63;
    const int wm = (w & 1) * 64, wn = (w >> 1) * 64;
    const int cq = lane >> 4, cc = lane & 15;
#pragma unroll
    for (int m = 0; m < 4; ++m)
#pragma unroll
    for (int r = 0; r < 4; ++r) {
        int orow = wm + m * 16 + cq * 4 + r;
        size_t rb = (size_t)(m0 + orow) * SIDIM + n0;
#pragma unroll
        for (int n = 0; n < 4; ++n) {
            float v = fmaxf(acc[m][n][r], 0.f);
            sh[rb + wn + n * 16 + cc] = (_Float16)(v * v);
        }
    }
}

// ------------------------------------------------ shared down (writes out base)
__global__ __launch_bounds__(256) void down_shared_kernel(
    const _Float16* __restrict__ sh, const _Float16* __restrict__ shdown,
    float* __restrict__ out) {
    const int m0 = blockIdx.y * 128;
    const int n0 = blockIdx.x * 128;
    const int tid = threadIdx.x;
    const int sc = ((tid & 7) ^ ((tid >> 3) & 7)) << 3;
    const int r0 = tid >> 3;
    const _Float16* aSrc[4]; const _Float16* bSrc[4];
#pragma unroll
    for (int i = 0; i < 4; ++i) {
        aSrc[i] = sh + (size_t)(m0 + i * 32 + r0) * SIDIM + sc;
        bSrc[i] = shdown + (size_t)(n0 + i * 32 + r0) * SIDIM + sc;
    }
    f4 acc[4][4] = {};
    gemm128<SIDIM>(aSrc, bSrc, acc);

    const int w = tid >> 6, lane = tid & 63;
    const int wm = (w & 1) * 64, wn = (w >> 1) * 64;
    const int cq = lane >> 4, cc = lane & 15;
#pragma unroll
    for (int m = 0; m < 4; ++m)
#pragma unroll
    for (int r = 0; r < 4; ++r) {
        int orow = wm + m * 16 + cq * 4 + r;
        size_t rb = (size_t)(m0 + orow) * HDIM + n0;
#pragma unroll
        for (int n = 0; n < 4; ++n)
            out[rb + wn + n * 16 + cc] = acc[m][n][r];
    }
}

// ------------------------------------------------ combine: out += sum_k slot
__global__ __launch_bounds__(256) void combine_kernel(
    const _Float16* __restrict__ slotout, float* __restrict__ out) {
    int gi = blockIdx.x * 256 + threadIdx.x;   // T*H/4 threads
    int t  = gi >> 8;                          // 256 float4 per row
    int c4 = gi & 255;
    size_t ob = (size_t)t * HDIM + c4 * 4;
    float4 v = *reinterpret_cast<const float4*>(out + ob);
    float s0 = v.x, s1 = v.y, s2 = v.z, s3 = v.w;
#pragma unroll
    for (int k = 0; k < TOPK; ++k) {
        h4 p = *reinterpret_cast<const h4*>(slotout + ((size_t)(t * TOPK + k)) * HDIM + c4 * 4);
        s0 += (float)p[0]; s1 += (float)p[1]; s2 += (float)p[2]; s3 += (float)p[3];
    }
    float4 r = {s0, s1, s2, s3};
    *reinterpret_cast<float4*>(out + ob) = r;
}

// ---------------------------------------------------------------------------
extern "C" void kernel_launch(void* const* d_in, const int* in_sizes, int n_in,
                              void* d_out, int out_size, void* d_ws, size_t ws_size,
                              hipStream_t stream) {
    const float* x     = (const float*)d_in[0];
    const float* gw    = (const float*)d_in[1];
    const float* bias  = (const float*)d_in[2];
    const float* wup   = (const float*)d_in[3];
    const float* wdown = (const float*)d_in[4];
    const float* sup   = (const float*)d_in[5];
    const float* sdown = (const float*)d_in[6];
    float* out = (float*)d_out;

    char* ws = (char*)d_ws;
    size_t off = 0;
    auto take = [&](size_t bytes) {
        char* p = ws + off;
        off = (off + bytes + 255) & ~(size_t)255;
        return p;
    };
    _Float16* xh      = (_Float16*)take((size_t)T_TOK * HDIM * 2);          // 8.4MB
    _Float16* whup    = (_Float16*)take((size_t)NEXP * IDIM * HDIM * 2);    // 33.6MB
    _Float16* whdown  = (_Float16*)take((size_t)NEXP * HDIM * IDIM * 2);    // 33.6MB
    _Float16* shupW   = (_Float16*)take((size_t)SIDIM * HDIM * 2);          // 4.2MB
    _Float16* shdownW = (_Float16*)take((size_t)HDIM * SIDIM * 2);          // 4.2MB
    _Float16* sh      = (_Float16*)take((size_t)T_TOK * SIDIM * 2);         // 16.8MB
    _Float16* hbuf    = (_Float16*)take((size_t)T_TOK * TOPK * IDIM * 2);   // 33.6MB
    int*   ids       = (int*)take((size_t)T_TOK * TOPK * 4);
    float* tw        = (float*)take((size_t)T_TOK * TOPK * 4);
    int*   tok_list  = (int*)take((size_t)NEXP * T_TOK * 4);
    float* wt_list   = (float*)take((size_t)NEXP * T_TOK * 4);
    int*   dest_list = (int*)take((size_t)NEXP * T_TOK * 4);
    int*   counts    = (int*)take(NEXP * 4);
    int*   offsets   = (int*)take((NEXP + 1) * 4);
    _Float16* slotout = (_Float16*)take((size_t)T_TOK * TOPK * HDIM * 2);   // 67.1MB
    const bool use_slot = off <= ws_size;

    // weight/activation conversions to fp16
    cvt_kernel<<<(T_TOK * HDIM / 4 + 255) / 256, 256, 0, stream>>>(x, xh, T_TOK * HDIM / 4);
    cvt_kernel<<<(NEXP * IDIM * HDIM / 4 + 255) / 256, 256, 0, stream>>>(wup, whup, NEXP * IDIM * HDIM / 4);
    cvt_kernel<<<(NEXP * HDIM * IDIM / 4 + 255) / 256, 256, 0, stream>>>(wdown, whdown, NEXP * HDIM * IDIM / 4);
    cvt_kernel<<<(SIDIM * HDIM / 4 + 255) / 256, 256, 0, stream>>>(sup, shupW, SIDIM * HDIM / 4);
    cvt_kernel<<<(HDIM * SIDIM / 4 + 255) / 256, 256, 0, stream>>>(sdown, shdownW, HDIM * SIDIM / 4);

    router_kernel<<<T_TOK / 4, 256, 0, stream>>>(x, gw, bias, ids, tw);
    build_lists_kernel<<<NEXP, 64, 0, stream>>>(ids, tw, tok_list, wt_list, dest_list, counts);
    scan_offsets_kernel<<<1, 64, 0, stream>>>(counts, offsets);

    up_routed_kernel<<<dim3(IDIM / 128, T_TOK / 128, NEXP), 256, 0, stream>>>(
        xh, whup, tok_list, wt_list, counts, offsets, hbuf);
    up_shared_kernel<<<dim3(SIDIM / 128, T_TOK / 128), 256, 0, stream>>>(xh, shupW, sh);
    down_shared_kernel<<<dim3(HDIM / 128, T_TOK / 128), 256, 0, stream>>>(sh, shdownW, out);

    if (use_slot) {
        down_routed_kernel<true><<<dim3(HDIM / 128, T_TOK / 128, NEXP), 256, 0, stream>>>(
            hbuf, whdown, dest_list, counts, offsets, slotout, out);
        combine_kernel<<<T_TOK * HDIM / 4 / 256, 256, 0, stream>>>(slotout, out);
    } else {
        down_routed_kernel<false><<<dim3(HDIM / 128, T_TOK / 128, NEXP), 256, 0, stream>>>(
            hbuf, whdown, dest_list, counts, offsets, slotout, out);
    }
}

// Round 3
// 357.918 us; speedup vs baseline: 1.2952x; 1.1169x over previous
//
#include <hip/hip_runtime.h>
#include <hip/hip_bf16.h>

// ---------------------------------------------------------------------------
// Nemotron-H MoE: T=4096 H=1024 E=32 (top-8, grouped 8x4) I=512, SI=2048.
// Round 3: router split into LDS-staged fp64 logits GEMM + wave selection
// (was 114us scatter-gather-bound). GEMM pipeline unchanged from round 2.
// ---------------------------------------------------------------------------

typedef _Float16 h8 __attribute__((ext_vector_type(8)));
typedef _Float16 h4 __attribute__((ext_vector_type(4)));
typedef float f4 __attribute__((ext_vector_type(4)));

#define T_TOK 4096
#define HDIM  1024
#define NEXP  32
#define IDIM  512
#define SIDIM 2048
#define TOPK  8

// async global->LDS, 16B per lane; LDS dest = wave-uniform base + lane*16
__device__ __forceinline__ void gload16(const void* g, void* l) {
    __builtin_amdgcn_global_load_lds(
        (const __attribute__((address_space(1))) void*)g,
        (__attribute__((address_space(3))) void*)l, 16, 0, 0);
}

// ---------------------------------------------------------------- fp32->fp16
__global__ void cvt_kernel(const float* __restrict__ in, _Float16* __restrict__ o, int n4) {
    int i = blockIdx.x * 256 + threadIdx.x;
    if (i < n4) {
        float4 v = reinterpret_cast<const float4*>(in)[i];
        h4 h; h[0] = (_Float16)v.x; h[1] = (_Float16)v.y; h[2] = (_Float16)v.z; h[3] = (_Float16)v.w;
        reinterpret_cast<h4*>(o)[i] = h;
    }
}

// ---------------------------------------------------------------- router logits
// fp64 logits[t][e] = sum_k x[t][k]*gw[e][k], LDS-staged (coalesced loads,
// conflict-free LDS reads). 16 tokens/block, 256 blocks, 2 acc/thread.
__global__ __launch_bounds__(256) void logits_kernel(
    const float* __restrict__ x, const float* __restrict__ gw,
    double* __restrict__ logits) {
    const int t0  = blockIdx.x * 16;
    const int tid = threadIdx.x;
    __shared__ double xS[16][66];
    __shared__ double gS[32][65];
    const int e  = tid & 31;
    const int tg = tid >> 5;        // 0..7
    const int tA = tg * 2, tB = tg * 2 + 1;
    double acc0 = 0.0, acc1 = 0.0;

    for (int kc = 0; kc < HDIM; kc += 64) {
        // stage x chunk: 16x64 floats, 4 per thread, coalesced
        {
            int r = tid >> 4, c0 = (tid & 15) * 4;
            float4 v = *reinterpret_cast<const float4*>(x + (size_t)(t0 + r) * HDIM + kc + c0);
            xS[r][c0]     = (double)v.x;
            xS[r][c0 + 1] = (double)v.y;
            xS[r][c0 + 2] = (double)v.z;
            xS[r][c0 + 3] = (double)v.w;
        }
        // stage gw chunk: 32x64 floats, 8 per thread, coalesced
        {
            int r = tid >> 3, c0 = (tid & 7) * 8;
            const float* gp = gw + (size_t)r * HDIM + kc + c0;
            float4 v0 = *reinterpret_cast<const float4*>(gp);
            float4 v1 = *reinterpret_cast<const float4*>(gp + 4);
            gS[r][c0]     = (double)v0.x;
            gS[r][c0 + 1] = (double)v0.y;
            gS[r][c0 + 2] = (double)v0.z;
            gS[r][c0 + 3] = (double)v0.w;
            gS[r][c0 + 4] = (double)v1.x;
            gS[r][c0 + 5] = (double)v1.y;
            gS[r][c0 + 6] = (double)v1.z;
            gS[r][c0 + 7] = (double)v1.w;
        }
        __syncthreads();
#pragma unroll
        for (int k = 0; k < 64; ++k) {
            double g = gS[e][k];
            acc0 = fma(g, xS[tA][k], acc0);
            acc1 = fma(g, xS[tB][k], acc1);
        }
        __syncthreads();
    }
    logits[(size_t)(t0 + tA) * NEXP + e] = acc0;
    logits[(size_t)(t0 + tB) * NEXP + e] = acc1;
}

// ---------------------------------------------------------------- selection
// one wave per token; fp64 sigmoid + grouped top-k (verified round-1 logic).
__global__ __launch_bounds__(256) void select_kernel(
    const double* __restrict__ logits, const float* __restrict__ bias,
    int* __restrict__ topk_ids, float* __restrict__ topk_w) {
    const int wid  = threadIdx.x >> 6;
    const int lane = threadIdx.x & 63;
    const int t    = blockIdx.x * 4 + wid;

    __shared__ double s_s[4][32];
    __shared__ double s_sfc[4][32];
    if (lane < 32) {
        double acc = logits[(size_t)t * NEXP + lane];
        double sg = 1.0 / (1.0 + exp(-acc));
        s_s[wid][lane]   = sg;
        s_sfc[wid][lane] = sg + (double)bias[lane];
    }
    __syncthreads();

    if (lane == 0) {
        double gsc[8];
        for (int g = 0; g < 8; ++g) {
            double m1 = -1e300, m2 = -1e300;
            for (int j = 0; j < 4; ++j) {
                double v = s_sfc[wid][g * 4 + j];
                if (v > m1) { m2 = m1; m1 = v; } else if (v > m2) { m2 = v; }
            }
            gsc[g] = m1 + m2;
        }
        bool gsel[8] = {};
        for (int r = 0; r < 4; ++r) {
            int best = 0; double bv = -1e300;
            for (int g = 0; g < 8; ++g)
                if (!gsel[g] && gsc[g] > bv) { bv = gsc[g]; best = g; }
            gsel[best] = true;
        }
        bool esel[32];
        for (int i2 = 0; i2 < 32; ++i2) esel[i2] = false;
        int ids[8]; double wsum = 0.0;
        for (int r = 0; r < 8; ++r) {
            int best = 0; double bv = -1e300;
            for (int e2 = 0; e2 < 32; ++e2)
                if (gsel[e2 >> 2] && !esel[e2] && s_sfc[wid][e2] > bv) { bv = s_sfc[wid][e2]; best = e2; }
            esel[best] = true;
            ids[r] = best;
            wsum += s_s[wid][best];
        }
        for (int r = 0; r < 8; ++r) {
            topk_ids[t * TOPK + r] = ids[r];
            topk_w[t * TOPK + r] = (float)(s_s[wid][ids[r]] / wsum * 2.5);
        }
    }
}

// ------------------------------------------------------- per-expert token lists
__global__ void build_lists_kernel(const int* __restrict__ ids, const float* __restrict__ w,
                                   int* __restrict__ tok_list, float* __restrict__ wt_list,
                                   int* __restrict__ dest_list, int* __restrict__ counts) {
    const int e = blockIdx.x;
    const int lane = threadIdx.x;  // block of 64
    int base = 0;
    for (int t0 = 0; t0 < T_TOK; t0 += 64) {
        int t = t0 + lane;
        int found = -1;
#pragma unroll
        for (int k = 0; k < TOPK; ++k)
            if (ids[t * TOPK + k] == e) found = k;
        unsigned long long mask = __ballot(found >= 0);
        if (found >= 0) {
            int pos = base + __popcll(mask & ((1ull << lane) - 1ull));
            tok_list[e * T_TOK + pos]  = t;
            wt_list[e * T_TOK + pos]   = w[t * TOPK + found];
            dest_list[e * T_TOK + pos] = t * TOPK + found;
        }
        base += __popcll(mask);
    }
    if (lane == 0) counts[e] = base;
}

__global__ void scan_offsets_kernel(const int* __restrict__ counts, int* __restrict__ offsets) {
    if (threadIdx.x == 0) {
        int run = 0;
        for (int e = 0; e < NEXP; ++e) { offsets[e] = run; run += counts[e]; }
        offsets[NEXP] = run;
    }
}

// ---------------------------------------------------------------------------
// Core 128x128 GEMM tile, BK=64, 256 threads (4 waves, 64x64 each, 4x4
// 16x16x32_f16 fragments). Linear LDS staged via global_load_lds(16B);
// XOR chunk swizzle applied on the global SOURCE address.
// ---------------------------------------------------------------------------
template<int K>
__device__ __forceinline__ void gemm128(const _Float16* const (&aSrc)[4],
                                        const _Float16* const (&bSrc)[4],
                                        f4 (&acc)[4][4]) {
    __shared__ __attribute__((aligned(16))) _Float16 As[128 * 64];
    __shared__ __attribute__((aligned(16))) _Float16 Bs[128 * 64];
    const int tid  = threadIdx.x;
    const int w    = tid >> 6, lane = tid & 63;
    const int wm   = (w & 1) * 64, wn = (w >> 1) * 64;
    const int ra   = lane & 15, kq = lane >> 4;

    for (int kk = 0; kk < K; kk += 64) {
#pragma unroll
        for (int i = 0; i < 4; ++i) {
            gload16(aSrc[i] + kk, As + (size_t)(i * 256 + w * 64) * 8);
            gload16(bSrc[i] + kk, Bs + (size_t)(i * 256 + w * 64) * 8);
        }
        __syncthreads();
#pragma unroll
        for (int s = 0; s < 2; ++s) {
            h8 af[4], bf[4];
#pragma unroll
            for (int m = 0; m < 4; ++m) {
                int row = wm + m * 16 + ra;
                af[m] = *reinterpret_cast<const h8*>(As + row * 64 + (((s * 4 + kq) ^ (row & 7)) << 3));
            }
#pragma unroll
            for (int n = 0; n < 4; ++n) {
                int row = wn + n * 16 + ra;
                bf[n] = *reinterpret_cast<const h8*>(Bs + row * 64 + (((s * 4 + kq) ^ (row & 7)) << 3));
            }
#pragma unroll
            for (int m = 0; m < 4; ++m)
#pragma unroll
                for (int n = 0; n < 4; ++n)
                    acc[m][n] = __builtin_amdgcn_mfma_f32_16x16x32_f16(af[m], bf[n], acc[m][n], 0, 0, 0);
        }
        __syncthreads();
    }
}

// ------------------------------------------------ routed up: h = relu(xW)^2 * g
__global__ __launch_bounds__(256) void up_routed_kernel(
    const _Float16* __restrict__ xh, const _Float16* __restrict__ whup,
    const int* __restrict__ tok_list, const float* __restrict__ wt_list,
    const int* __restrict__ counts, const int* __restrict__ offsets,
    _Float16* __restrict__ hbuf) {
    const int e   = blockIdx.z;
    const int cnt = counts[e];
    const int m0  = blockIdx.y * 128;
    if (m0 >= cnt) return;
    const int n0   = blockIdx.x * 128;
    const int eoff = offsets[e];

    __shared__ int   tokS[128];
    __shared__ float wS[128];
    const int tid = threadIdx.x;
    if (tid < 128) {
        int row = m0 + tid;
        int cr  = row < cnt ? row : cnt - 1;
        tokS[tid] = tok_list[e * T_TOK + cr];
        wS[tid]   = row < cnt ? wt_list[e * T_TOK + row] : 0.f;
    }
    __syncthreads();

    const int sc = ((tid & 7) ^ ((tid >> 3) & 7)) << 3;
    const int r0 = tid >> 3;
    const _Float16* aSrc[4]; const _Float16* bSrc[4];
#pragma unroll
    for (int i = 0; i < 4; ++i) {
        aSrc[i] = xh + (size_t)tokS[i * 32 + r0] * HDIM + sc;
        bSrc[i] = whup + ((size_t)e * IDIM + n0 + i * 32 + r0) * HDIM + sc;
    }
    f4 acc[4][4] = {};
    gemm128<HDIM>(aSrc, bSrc, acc);

    const int w = tid >> 6, lane = tid & 63;
    const int wm = (w & 1) * 64, wn = (w >> 1) * 64;
    const int cq = lane >> 4, cc = lane & 15;
#pragma unroll
    for (int m = 0; m < 4; ++m)
#pragma unroll
    for (int r = 0; r < 4; ++r) {
        int orow = wm + m * 16 + cq * 4 + r;
        if (m0 + orow < cnt) {
            float g = wS[orow];
            size_t rb = (size_t)(eoff + m0 + orow) * IDIM + n0;
#pragma unroll
            for (int n = 0; n < 4; ++n) {
                float v = fmaxf(acc[m][n][r], 0.f);
                hbuf[rb + wn + n * 16 + cc] = (_Float16)(v * v * g);
            }
        }
    }
}

// ------------------------------------------------ routed down
template<bool SLOT>
__global__ __launch_bounds__(256) void down_routed_kernel(
    const _Float16* __restrict__ hbuf, const _Float16* __restrict__ whdown,
    const int* __restrict__ dest_list, const int* __restrict__ counts,
    const int* __restrict__ offsets, _Float16* __restrict__ slotout,
    float* __restrict__ out) {
    const int e   = blockIdx.z;
    const int cnt = counts[e];
    const int m0  = blockIdx.y * 128;
    if (m0 >= cnt) return;
    const int n0   = blockIdx.x * 128;
    const int eoff = offsets[e];

    __shared__ int dS[128];
    const int tid = threadIdx.x;
    if (tid < 128) {
        int row = m0 + tid;
        dS[tid] = dest_list[e * T_TOK + (row < cnt ? row : cnt - 1)];
    }
    // (dS is consumed only after gemm128's internal barriers)

    const int sc = ((tid & 7) ^ ((tid >> 3) & 7)) << 3;
    const int r0 = tid >> 3;
    const _Float16* aSrc[4]; const _Float16* bSrc[4];
#pragma unroll
    for (int i = 0; i < 4; ++i) {
        int row = m0 + i * 32 + r0;
        int cr  = row < cnt ? row : cnt - 1;
        aSrc[i] = hbuf + (size_t)(eoff + cr) * IDIM + sc;
        bSrc[i] = whdown + ((size_t)e * HDIM + n0 + i * 32 + r0) * IDIM + sc;
    }
    f4 acc[4][4] = {};
    gemm128<IDIM>(aSrc, bSrc, acc);

    const int w = tid >> 6, lane = tid & 63;
    const int wm = (w & 1) * 64, wn = (w >> 1) * 64;
    const int cq = lane >> 4, cc = lane & 15;
#pragma unroll
    for (int m = 0; m < 4; ++m)
#pragma unroll
    for (int r = 0; r < 4; ++r) {
        int orow = wm + m * 16 + cq * 4 + r;
        if (m0 + orow < cnt) {
            int d = dS[orow];
            if (SLOT) {
                size_t rb = (size_t)d * HDIM + n0;
#pragma unroll
                for (int n = 0; n < 4; ++n)
                    slotout[rb + wn + n * 16 + cc] = (_Float16)acc[m][n][r];
            } else {
                size_t rb = (size_t)(d >> 3) * HDIM + n0;
#pragma unroll
                for (int n = 0; n < 4; ++n)
                    atomicAdd(&out[rb + wn + n * 16 + cc], acc[m][n][r]);
            }
        }
    }
}

// ------------------------------------------------ shared up
__global__ __launch_bounds__(256) void up_shared_kernel(
    const _Float16* __restrict__ xh, const _Float16* __restrict__ shup,
    _Float16* __restrict__ sh) {
    const int m0 = blockIdx.y * 128;
    const int n0 = blockIdx.x * 128;
    const int tid = threadIdx.x;
    const int sc = ((tid & 7) ^ ((tid >> 3) & 7)) << 3;
    const int r0 = tid >> 3;
    const _Float16* aSrc[4]; const _Float16* bSrc[4];
#pragma unroll
    for (int i = 0; i < 4; ++i) {
        aSrc[i] = xh + (size_t)(m0 + i * 32 + r0) * HDIM + sc;
        bSrc[i] = shup + (size_t)(n0 + i * 32 + r0) * HDIM + sc;
    }
    f4 acc[4][4] = {};
    gemm128<HDIM>(aSrc, bSrc, acc);

    const int w = tid >> 6, lane = tid & 63;
    const int wm = (w & 1) * 64, wn = (w >> 1) * 64;
    const int cq = lane >> 4, cc = lane & 15;
#pragma unroll
    for (int m = 0; m < 4; ++m)
#pragma unroll
    for (int r = 0; r < 4; ++r) {
        int orow = wm + m * 16 + cq * 4 + r;
        size_t rb = (size_t)(m0 + orow) * SIDIM + n0;
#pragma unroll
        for (int n = 0; n < 4; ++n) {
            float v = fmaxf(acc[m][n][r], 0.f);
            sh[rb + wn + n * 16 + cc] = (_Float16)(v * v);
        }
    }
}

// ------------------------------------------------ shared down (writes out base)
__global__ __launch_bounds__(256) void down_shared_kernel(
    const _Float16* __restrict__ sh, const _Float16* __restrict__ shdown,
    float* __restrict__ out) {
    const int m0 = blockIdx.y * 128;
    const int n0 = blockIdx.x * 128;
    const int tid = threadIdx.x;
    const int sc = ((tid & 7) ^ ((tid >> 3) & 7)) << 3;
    const int r0 = tid >> 3;
    const _Float16* aSrc[4]; const _Float16* bSrc[4];
#pragma unroll
    for (int i = 0; i < 4; ++i) {
        aSrc[i] = sh + (size_t)(m0 + i * 32 + r0) * SIDIM + sc;
        bSrc[i] = shdown + (size_t)(n0 + i * 32 + r0) * SIDIM + sc;
    }
    f4 acc[4][4] = {};
    gemm128<SIDIM>(aSrc, bSrc, acc);

    const int w = tid >> 6, lane = tid & 63;
    const int wm = (w & 1) * 64, wn = (w >> 1) * 64;
    const int cq = lane >> 4, cc = lane & 15;
#pragma unroll
    for (int m = 0; m < 4; ++m)
#pragma unroll
    for (int r = 0; r < 4; ++r) {
        int orow = wm + m * 16 + cq * 4 + r;
        size_t rb = (size_t)(m0 + orow) * HDIM + n0;
#pragma unroll
        for (int n = 0; n < 4; ++n)
            out[rb + wn + n * 16 + cc] = acc[m][n][r];
    }
}

// ------------------------------------------------ combine: out += sum_k slot
__global__ __launch_bounds__(256) void combine_kernel(
    const _Float16* __restrict__ slotout, float* __restrict__ out) {
    int gi = blockIdx.x * 256 + threadIdx.x;   // T*H/4 threads
    int t  = gi >> 8;                          // 256 float4 per row
    int c4 = gi & 255;
    size_t ob = (size_t)t * HDIM + c4 * 4;
    float4 v = *reinterpret_cast<const float4*>(out + ob);
    float s0 = v.x, s1 = v.y, s2 = v.z, s3 = v.w;
#pragma unroll
    for (int k = 0; k < TOPK; ++k) {
        h4 p = *reinterpret_cast<const h4*>(slotout + ((size_t)(t * TOPK + k)) * HDIM + c4 * 4);
        s0 += (float)p[0]; s1 += (float)p[1]; s2 += (float)p[2]; s3 += (float)p[3];
    }
    float4 r = {s0, s1, s2, s3};
    *reinterpret_cast<float4*>(out + ob) = r;
}

// ---------------------------------------------------------------------------
extern "C" void kernel_launch(void* const* d_in, const int* in_sizes, int n_in,
                              void* d_out, int out_size, void* d_ws, size_t ws_size,
                              hipStream_t stream) {
    const float* x     = (const float*)d_in[0];
    const float* gw    = (const float*)d_in[1];
    const float* bias  = (const float*)d_in[2];
    const float* wup   = (const float*)d_in[3];
    const float* wdown = (const float*)d_in[4];
    const float* sup   = (const float*)d_in[5];
    const float* sdown = (const float*)d_in[6];
    float* out = (float*)d_out;

    char* ws = (char*)d_ws;
    size_t off = 0;
    auto take = [&](size_t bytes) {
        char* p = ws + off;
        off = (off + bytes + 255) & ~(size_t)255;
        return p;
    };
    _Float16* xh      = (_Float16*)take((size_t)T_TOK * HDIM * 2);          // 8.4MB
    _Float16* whup    = (_Float16*)take((size_t)NEXP * IDIM * HDIM * 2);    // 33.6MB
    _Float16* whdown  = (_Float16*)take((size_t)NEXP * HDIM * IDIM * 2);    // 33.6MB
    _Float16* shupW   = (_Float16*)take((size_t)SIDIM * HDIM * 2);          // 4.2MB
    _Float16* shdownW = (_Float16*)take((size_t)HDIM * SIDIM * 2);          // 4.2MB
    _Float16* sh      = (_Float16*)take((size_t)T_TOK * SIDIM * 2);         // 16.8MB
    _Float16* hbuf    = (_Float16*)take((size_t)T_TOK * TOPK * IDIM * 2);   // 33.6MB
    double* logits   = (double*)take((size_t)T_TOK * NEXP * 8);             // 1.0MB
    int*   ids       = (int*)take((size_t)T_TOK * TOPK * 4);
    float* tw        = (float*)take((size_t)T_TOK * TOPK * 4);
    int*   tok_list  = (int*)take((size_t)NEXP * T_TOK * 4);
    float* wt_list   = (float*)take((size_t)NEXP * T_TOK * 4);
    int*   dest_list = (int*)take((size_t)NEXP * T_TOK * 4);
    int*   counts    = (int*)take(NEXP * 4);
    int*   offsets   = (int*)take((NEXP + 1) * 4);
    _Float16* slotout = (_Float16*)take((size_t)T_TOK * TOPK * HDIM * 2);   // 67.1MB
    const bool use_slot = off <= ws_size;

    // router first (logits GEMM + selection), then conversions
    logits_kernel<<<T_TOK / 16, 256, 0, stream>>>(x, gw, logits);
    select_kernel<<<T_TOK / 4, 256, 0, stream>>>(logits, bias, ids, tw);
    build_lists_kernel<<<NEXP, 64, 0, stream>>>(ids, tw, tok_list, wt_list, dest_list, counts);
    scan_offsets_kernel<<<1, 64, 0, stream>>>(counts, offsets);

    // weight/activation conversions to fp16
    cvt_kernel<<<(T_TOK * HDIM / 4 + 255) / 256, 256, 0, stream>>>(x, xh, T_TOK * HDIM / 4);
    cvt_kernel<<<(NEXP * IDIM * HDIM / 4 + 255) / 256, 256, 0, stream>>>(wup, whup, NEXP * IDIM * HDIM / 4);
    cvt_kernel<<<(NEXP * HDIM * IDIM / 4 + 255) / 256, 256, 0, stream>>>(wdown, whdown, NEXP * HDIM * IDIM / 4);
    cvt_kernel<<<(SIDIM * HDIM / 4 + 255) / 256, 256, 0, stream>>>(sup, shupW, SIDIM * HDIM / 4);
    cvt_kernel<<<(HDIM * SIDIM / 4 + 255) / 256, 256, 0, stream>>>(sdown, shdownW, HDIM * SIDIM / 4);

    up_routed_kernel<<<dim3(IDIM / 128, T_TOK / 128, NEXP), 256, 0, stream>>>(
        xh, whup, tok_list, wt_list, counts, offsets, hbuf);
    up_shared_kernel<<<dim3(SIDIM / 128, T_TOK / 128), 256, 0, stream>>>(xh, shupW, sh);
    down_shared_kernel<<<dim3(HDIM / 128, T_TOK / 128), 256, 0, stream>>>(sh, shdownW, out);

    if (use_slot) {
        down_routed_kernel<true><<<dim3(HDIM / 128, T_TOK / 128, NEXP), 256, 0, stream>>>(
            hbuf, whdown, dest_list, counts, offsets, slotout, out);
        combine_kernel<<<T_TOK * HDIM / 4 / 256, 256, 0, stream>>>(slotout, out);
    } else {
        down_routed_kernel<false><<<dim3(HDIM / 128, T_TOK / 128, NEXP), 256, 0, stream>>>(
            hbuf, whdown, dest_list, counts, offsets, slotout, out);
    }
}